// Round 7
// baseline (439.005 us; speedup 1.0000x reference)
//
#include <hip/hip_runtime.h>
#include <math.h>

// Problem constants
#define BB 2
#define LL 2048
#define DD 2048
#define HH 16
#define KVH 8
#define HDIM 128
#define SCALE_F 0.08838834764831845f   // 128^-0.5
#define EPS_F 1e-5f
#define LOG2E 1.4426950408889634f
#define SMAX_F 17.0f                    // fixed softmax max (log2 domain); |s*SC2| <= 16.5
#define QKVW 4096                       // fused qkv row width: 16q + 8k + 8v heads

typedef unsigned short u16;
typedef __attribute__((ext_vector_type(8))) short short8;
typedef __attribute__((ext_vector_type(4))) float f32x4;
typedef __attribute__((ext_vector_type(16))) float f32x16;

#define MFMA16(a, b, c) __builtin_amdgcn_mfma_f32_16x16x32_bf16((a), (b), (c), 0, 0, 0)
#define MFMA32(a, b, c) __builtin_amdgcn_mfma_f32_32x32x16_bf16((a), (b), (c), 0, 0, 0)

__device__ __forceinline__ float b2f(u16 u) {
    union { unsigned int i; float f; } x;
    x.i = ((unsigned int)u) << 16;
    return x.f;
}
__device__ __forceinline__ u16 f2b(float f) {
    unsigned int x = __float_as_uint(f);
    unsigned int r = x + 0x7FFFu + ((x >> 16) & 1u);   // round-to-nearest-even
    return (u16)(r >> 16);
}
__device__ __forceinline__ u16 f2b_fast(float f) {     // round-half-up, 2 VALU
    return (u16)((__float_as_uint(f) + 0x8000u) >> 16);
}
// async global->LDS, 16B per lane; LDS dest = base + lane*16 (HW-fixed)
__device__ __forceinline__ void g2l(const u16* g, u16* l) {
    __builtin_amdgcn_global_load_lds(
        (const __attribute__((address_space(1))) unsigned int*)g,
        (__attribute__((address_space(3))) unsigned int*)l, 16, 0, 0);
}

// ---------------------------------------------------------------------------
// Fused prep: [0,8192) x fp32->bf16 | [8192,11264) weight transposes |
// [11264,11776) rope tables. All independent; one launch.
// ---------------------------------------------------------------------------
__global__ __launch_bounds__(256) void prep_kernel(const float* __restrict__ x,
                                                   u16* __restrict__ xb,
                                                   const float* __restrict__ wq,
                                                   const float* __restrict__ wk,
                                                   const float* __restrict__ wv,
                                                   const float* __restrict__ wo,
                                                   u16* __restrict__ wqkvT,
                                                   u16* __restrict__ woT,
                                                   float* __restrict__ ct,
                                                   float* __restrict__ st) {
    __shared__ u16 t[64 * 65];
    const int blk = blockIdx.x, tid = threadIdx.x;
    if (blk < 8192) {
        // convert x -> bf16
        int i = (blk * 256 + tid) * 4;
        float4 v = *(const float4*)(x + i);
        unsigned int p0 = (unsigned int)f2b(v.x) | ((unsigned int)f2b(v.y) << 16);
        unsigned int p1 = (unsigned int)f2b(v.z) | ((unsigned int)f2b(v.w) << 16);
        uint2 pk; pk.x = p0; pk.y = p1;
        *(uint2*)(xb + i) = pk;
    } else if (blk < 11264) {
        // weight transpose+convert: in [R=2048 rows][C cols] -> out [C][2048]
        int j = blk - 8192;
        const float* in; u16* out; int C, bx, by;
        if (j < 1024)      { in = wq; out = wqkvT;                      C = 2048; bx = j & 31; by = j >> 5; }
        else if (j < 1536) { j -= 1024; in = wk; out = wqkvT + (size_t)2048 * DD; C = 1024; bx = j & 15; by = j >> 4; }
        else if (j < 2048) { j -= 1536; in = wv; out = wqkvT + (size_t)3072 * DD; C = 1024; bx = j & 15; by = j >> 4; }
        else               { j -= 2048; in = wo; out = woT;                      C = 2048; bx = j & 31; by = j >> 5; }
        int c0 = bx * 64, r0 = by * 64;
#pragma unroll
        for (int i = 0; i < 16; i++) {
            int idx = tid + i * 256;
            int r = idx >> 6, c = idx & 63;
            t[r * 65 + c] = f2b(in[(size_t)(r0 + r) * C + c0 + c]);
        }
        __syncthreads();
#pragma unroll
        for (int i = 0; i < 16; i++) {
            int idx = tid + i * 256;
            int r = idx >> 6, c = idx & 63;
            out[(size_t)(c0 + r) * DD + r0 + c] = t[c * 65 + r];
        }
    } else {
        // rope tables, numpy fp32 semantics: fp32 freq (correctly rounded),
        // fp32 angle multiply, correctly-rounded cos/sin of that fp32 angle
        int i = (blk - 11264) * 256 + tid;   // i < LL*64
        int pos = i >> 6, d = i & 63;
        float freq = (float)pow(10000.0, (double)d * (1.0 / 64.0));
        float ang = (float)pos * freq;
        double a = (double)ang;
        ct[i] = (float)cos(a);
        st[i] = (float)sin(a);
    }
}

// ---------------------------------------------------------------------------
// GEMM: C[M,N] = A[M,K] @ Bt[N,K]^T, m97 structure, bf16 out. 128x128 tile.
// ---------------------------------------------------------------------------
__global__ __launch_bounds__(256) void gemm_bt(const u16* __restrict__ A,
                                               const u16* __restrict__ Bt,
                                               u16* __restrict__ C, int M, int N, int K) {
    __shared__ __align__(16) u16 As[128 * 32];
    __shared__ __align__(16) u16 Bs[128 * 32];
    const int tid = threadIdx.x;
    const int w = tid >> 6, lane = tid & 63;
    const int lm = lane & 15, lq = lane >> 4;
    const int bn0 = blockIdx.x * 128, bm0 = blockIdx.y * 128;
    const int wm = (w >> 1) * 64, wn = (w & 1) * 64;

    f32x4 acc[4][4];
#pragma unroll
    for (int i = 0; i < 4; i++)
#pragma unroll
        for (int j = 0; j < 4; j++) acc[i][j] = (f32x4){0.f, 0.f, 0.f, 0.f};

    const int sr = w * 32 + (lane >> 2);
    const int scc = lane & 3;
    const u16* ga = A + (size_t)(bm0 + sr) * K + scc * 8;
    const u16* gb = Bt + (size_t)(bn0 + sr) * K + scc * 8;
    u16* lA = &As[w * 1024];
    u16* lB = &Bs[w * 1024];

    for (int k0 = 0; k0 < K; k0 += 32) {
        __syncthreads();
        g2l(ga + k0, lA);
        g2l(ga + (size_t)16 * K + k0, lA + 512);
        g2l(gb + k0, lB);
        g2l(gb + (size_t)16 * K + k0, lB + 512);
        __syncthreads();

        short8 af[4], bf[4];
#pragma unroll
        for (int mt = 0; mt < 4; mt++)
            af[mt] = *(const short8*)(&As[(wm + mt * 16 + lm) * 32 + lq * 8]);
#pragma unroll
        for (int nt = 0; nt < 4; nt++)
            bf[nt] = *(const short8*)(&Bs[(wn + nt * 16 + lm) * 32 + lq * 8]);
#pragma unroll
        for (int mt = 0; mt < 4; mt++)
#pragma unroll
            for (int nt = 0; nt < 4; nt++) acc[mt][nt] = MFMA16(af[mt], bf[nt], acc[mt][nt]);
    }

#pragma unroll
    for (int mt = 0; mt < 4; mt++)
#pragma unroll
        for (int nt = 0; nt < 4; nt++)
#pragma unroll
            for (int r = 0; r < 4; r++) {
                int row = bm0 + wm + mt * 16 + lq * 4 + r;
                int col = bn0 + wn + nt * 16 + lm;
                C[(size_t)row * N + col] = f2b(acc[mt][nt][r]);
            }
}

// ---------------------------------------------------------------------------
// Split-K GEMM (fp32 atomic out): grid.z halves K; 1024 blocks = 4/CU so the
// barrier drain is hidden (2 blocks/CU ran at 299 TF vs 597 at 4/CU).
// Exactly 2 commutative fp32 adds per element -> replay-deterministic.
// ---------------------------------------------------------------------------
__global__ __launch_bounds__(256) void gemm_bt_sk(const u16* __restrict__ A,
                                                  const u16* __restrict__ Bt,
                                                  float* __restrict__ C, int M, int N, int K) {
    __shared__ __align__(16) u16 As[128 * 32];
    __shared__ __align__(16) u16 Bs[128 * 32];
    const int tid = threadIdx.x;
    const int w = tid >> 6, lane = tid & 63;
    const int lm = lane & 15, lq = lane >> 4;
    const int bn0 = blockIdx.x * 128, bm0 = blockIdx.y * 128;
    const int wm = (w >> 1) * 64, wn = (w & 1) * 64;
    const int kbeg = blockIdx.z * (K >> 1), kend = kbeg + (K >> 1);

    f32x4 acc[4][4];
#pragma unroll
    for (int i = 0; i < 4; i++)
#pragma unroll
        for (int j = 0; j < 4; j++) acc[i][j] = (f32x4){0.f, 0.f, 0.f, 0.f};

    const int sr = w * 32 + (lane >> 2);
    const int scc = lane & 3;
    const u16* ga = A + (size_t)(bm0 + sr) * K + scc * 8;
    const u16* gb = Bt + (size_t)(bn0 + sr) * K + scc * 8;
    u16* lA = &As[w * 1024];
    u16* lB = &Bs[w * 1024];

    for (int k0 = kbeg; k0 < kend; k0 += 32) {
        __syncthreads();
        g2l(ga + k0, lA);
        g2l(ga + (size_t)16 * K + k0, lA + 512);
        g2l(gb + k0, lB);
        g2l(gb + (size_t)16 * K + k0, lB + 512);
        __syncthreads();

        short8 af[4], bf[4];
#pragma unroll
        for (int mt = 0; mt < 4; mt++)
            af[mt] = *(const short8*)(&As[(wm + mt * 16 + lm) * 32 + lq * 8]);
#pragma unroll
        for (int nt = 0; nt < 4; nt++)
            bf[nt] = *(const short8*)(&Bs[(wn + nt * 16 + lm) * 32 + lq * 8]);
#pragma unroll
        for (int mt = 0; mt < 4; mt++)
#pragma unroll
            for (int nt = 0; nt < 4; nt++) acc[mt][nt] = MFMA16(af[mt], bf[nt], acc[mt][nt]);
    }

#pragma unroll
    for (int mt = 0; mt < 4; mt++)
#pragma unroll
        for (int nt = 0; nt < 4; nt++)
#pragma unroll
            for (int r = 0; r < 4; r++) {
                int row = bm0 + wm + mt * 16 + lq * 4 + r;
                int col = bn0 + wn + nt * 16 + lm;
                atomicAdd(&C[(size_t)row * N + col], acc[mt][nt][r]);
            }
}

// ---------------------------------------------------------------------------
// Fused RoPE+RMSNorm (blocks [0,24576)) + V transpose (blocks [24576,25600)).
// Independent regions of qkv: rope touches cols 0..3071, tv reads 3072..4095.
// ---------------------------------------------------------------------------
__global__ __launch_bounds__(256) void ropetv_kernel(u16* __restrict__ qkv,
                                                     u16* __restrict__ vt,
                                                     const float* __restrict__ qw,
                                                     const float* __restrict__ kw,
                                                     const float* __restrict__ ct,
                                                     const float* __restrict__ st) {
    __shared__ u16 t[64 * 65];
    const int blk = blockIdx.x, tid = threadIdx.x;
    if (blk < 24576) {
        int slot = blk * 4 + (tid >> 6);
        int lane = tid & 63;
        int hh = slot % (HH + KVH);
        int row = slot / (HH + KVH);   // [0, B*L)
        int pos = row & (LL - 1);

        u16* base = qkv + (size_t)row * QKVW + hh * HDIM;
        const float* w = (hh < HH) ? qw : kw;

        float x1 = b2f(base[lane]), x2 = b2f(base[lane + 64]);
        float c = ct[pos * 64 + lane], s = st[pos * 64 + lane];
        float r1 = x1 * c - x2 * s;
        float r2 = x2 * c + x1 * s;
        float ss = r1 * r1 + r2 * r2;
#pragma unroll
        for (int m = 1; m < 64; m <<= 1) ss += __shfl_xor(ss, m, 64);
        float sc = 1.0f / sqrtf(ss * (1.0f / 128.0f) + EPS_F);
        base[lane] = f2b(r1 * sc * w[lane]);
        base[lane + 64] = f2b(r2 * sc * w[lane + 64]);
    } else {
        // V cols of qkv (3072 + g*128 + d) -> vt [b*8+g][d][l]
        int j = blk - 24576;
        int bx = j & 31, by = (j >> 5) & 1, bg = j >> 6;
        int l0 = bx * 64, d0 = by * 64;
        int b = bg >> 3, g = bg & 7;
        const u16* src = qkv + (size_t)b * LL * QKVW + 3072 + g * HDIM;
        u16* dst = vt + (size_t)bg * HDIM * LL;
#pragma unroll
        for (int i = 0; i < 16; i++) {
            int idx = tid + i * 256;
            int r = idx >> 6, c = idx & 63;
            t[r * 65 + c] = src[(size_t)(l0 + r) * QKVW + d0 + c];
        }
        __syncthreads();
#pragma unroll
        for (int i = 0; i < 16; i++) {
            int idx = tid + i * 256;
            int r = idx >> 6, c = idx & 63;   // r = dim, c = key
            dst[(size_t)(d0 + r) * LL + l0 + c] = t[c * 65 + r];
        }
    }
}

// ---------------------------------------------------------------------------
// Flash attention, 32x32x16 MFMA, fixed-max softmax (round-6 verified).
// Block = 256 threads (4 waves) = 128 q-rows. 64-key tiles. 3 barriers/tile
// (barrier (c) is required: P staging ds_write -> ds_read_b128 ordering).
// LDS = 48KB. Grid 512 blocks = 2/CU.
// ---------------------------------------------------------------------------
__global__ __launch_bounds__(256, 2) void attn_kernel(const u16* __restrict__ qkv,
                                                      const u16* __restrict__ vt,
                                                      u16* __restrict__ ob) {
    __shared__ __align__(16) u16 Kt[64 * 128];   // [key][dim] 16 granules/row
    __shared__ __align__(16) u16 Vt[128 * 64];   // [dim][key] 8 granules/row
    __shared__ __align__(16) u16 Ps[4][32 * 64]; // per-wave P, key ^= (row&7)<<3

    const int tid = threadIdx.x, w = tid >> 6, lane = tid & 63;
    const int l31 = lane & 31, lh = lane >> 5;
    const int q0 = blockIdx.x * 128;
    const int bh = blockIdx.y, b = bh >> 4, hd = bh & 15, g = hd >> 1;

    const u16* kbase = qkv + (size_t)b * LL * QKVW + 2048 + g * HDIM;
    const u16* vtbase = vt + (size_t)(b * KVH + g) * HDIM * LL;

    const int krl = lane >> 4, kgl = lane & 15;
    const int vrl = lane >> 3, vgl = lane & 7;

    // Q fragments (A of 32x32x16: m=lane&31, k = kk*16 + lh*8 + j)
    const int qrow = q0 + w * 32 + l31;
    short8 aq[8];
    {
        const u16* qp = qkv + (size_t)(b * LL + qrow) * QKVW + hd * HDIM + lh * 8;
#pragma unroll
        for (int kk = 0; kk < 8; kk++) aq[kk] = *(const short8*)(qp + kk * 16);
    }

    f32x16 o[4];
#pragma unroll
    for (int i = 0; i < 4; i++)
#pragma unroll
        for (int r = 0; r < 16; r++) o[i][r] = 0.f;
    float psum[16];
#pragma unroll
    for (int r = 0; r < 16; r++) psum[r] = 0.f;
    const float SC2 = SCALE_F * LOG2E;

    for (int t = 0; t < LL / 64; t++) {
        __syncthreads();   // (a) prior tile's Kt/Vt fragment reads done
#pragma unroll
        for (int ch = 0; ch < 4; ch++) {
            int r = w * 16 + ch * 4 + krl;
            int gc = kgl ^ (r & 15);
            g2l(kbase + (size_t)(t * 64 + r) * QKVW + gc * 8,
                &Kt[(w * 16 + ch * 4) * 128]);
        }
#pragma unroll
        for (int ch = 0; ch < 4; ch++) {
            int r = w * 32 + ch * 8 + vrl;
            int gc = vgl ^ (r & 7);
            g2l(vtbase + (size_t)r * LL + t * 64 + gc * 8,
                &Vt[(w * 32 + ch * 8) * 64]);
        }
        __syncthreads();   // (b) staging complete

        // S = Q @ K^T  (2 key-tiles of 32)
        f32x16 s[2];
#pragma unroll
        for (int kt = 0; kt < 2; kt++) {
#pragma unroll
            for (int r = 0; r < 16; r++) s[kt][r] = 0.f;
            int key = kt * 32 + l31;
#pragma unroll
            for (int kk = 0; kk < 8; kk++) {
                int gg = (kk * 2 + lh) ^ (key & 15);
                short8 bf = *(const short8*)(&Kt[key * 128 + gg * 8]);
                s[kt] = MFMA32(aq[kk], bf, s[kt]);
            }
        }

        // P = exp2(s*SC2 - 17); lane-partial row sums; stage to per-wave Ps
#pragma unroll
        for (int kt = 0; kt < 2; kt++) {
            int key = kt * 32 + l31;
#pragma unroll
            for (int r = 0; r < 16; r++) {
                float p = exp2f(fmaf(s[kt][r], SC2, -SMAX_F));
                psum[r] += p;
                int row = (r & 3) + 8 * (r >> 2) + 4 * lh;
                Ps[w][row * 64 + (key ^ ((row & 7) << 3))] = f2b_fast(p);
            }
        }
        __syncthreads();   // (c) required: P writes visible before b128 reads

        // O += P @ V
#pragma unroll
        for (int kc = 0; kc < 4; kc++) {
            int gp = ((kc * 2 + lh) ^ (l31 & 7)) * 8;
            short8 pa = *(const short8*)(&Ps[w][l31 * 64 + gp]);
#pragma unroll
            for (int dn = 0; dn < 4; dn++) {
                int d = dn * 32 + l31;
                int gv = ((kc * 2 + lh) ^ (d & 7)) * 8;
                short8 bv = *(const short8*)(&Vt[d * 64 + gv]);
                o[dn] = MFMA32(pa, bv, o[dn]);
            }
        }
    }

    // deferred row-sum reduce across the 32 lanes sharing lh
#pragma unroll
    for (int m = 1; m < 32; m <<= 1)
#pragma unroll
        for (int r = 0; r < 16; r++) psum[r] += __shfl_xor(psum[r], m, 32);
    float inv[16];
#pragma unroll
    for (int r = 0; r < 16; r++) inv[r] = 1.0f / psum[r];

    // O: col = dim = dn*32 + l31, row = (r&3)+8*(r>>2)+4*lh
    u16* obase = ob + (size_t)(b * LL + q0 + w * 32) * (HH * HDIM) + hd * HDIM;
#pragma unroll
    for (int dn = 0; dn < 4; dn++)
#pragma unroll
        for (int r = 0; r < 16; r++) {
            int row = (r & 3) + 8 * (r >> 2) + 4 * lh;
            obase[(size_t)row * (HH * HDIM) + dn * 32 + l31] = f2b(o[dn][r] * inv[r]);
        }
}

// ---------------------------------------------------------------------------
extern "C" void kernel_launch(void* const* d_in, const int* in_sizes, int n_in,
                              void* d_out, int out_size, void* d_ws, size_t ws_size,
                              hipStream_t stream) {
    const float* x  = (const float*)d_in[0];
    const float* wq = (const float*)d_in[1];
    const float* wk = (const float*)d_in[2];
    const float* wv = (const float*)d_in[3];
    const float* wo = (const float*)d_in[4];
    const float* qn = (const float*)d_in[5];
    const float* kn = (const float*)d_in[6];

    u16* ws = (u16*)d_ws;
    const size_t SZ_X = (size_t)BB * LL * DD;          // 8388608
    u16* xb    = ws;                         // SZ_X (later reused as att)
    u16* qkv   = xb + SZ_X;                  // B*L*4096 = 16.8M
    u16* wqkvT = qkv + (size_t)BB * LL * QKVW;  // 4096*2048 (later reused as vt)
    u16* woT   = wqkvT + (size_t)QKVW * DD;  // 2048*2048
    float* ct  = (float*)(woT + (size_t)DD * DD);   // LL*64 floats
    float* st  = ct + (size_t)LL * 64;
    u16* att = xb;
    u16* vt  = wqkvT;   // dead after fused QKV GEMM

    // 1. fused prep: x convert + 4 weight transposes + rope tables
    prep_kernel<<<dim3(11776), dim3(256), 0, stream>>>(x, xb, wq, wk, wv, wo,
                                                       wqkvT, woT, ct, st);
    // 2. fused QKV projection: [B*L, 4096] = xb @ wqkvT^T
    gemm_bt<<<dim3(QKVW / 128, BB * LL / 128), dim3(256), 0, stream>>>(xb, wqkvT, qkv, BB * LL, QKVW, DD);
    // 3. fused rope+rmsnorm (q,k) + V transpose
    ropetv_kernel<<<dim3(25600), dim3(256), 0, stream>>>(qkv, vt, qn, kn, ct, st);
    // 4. attention
    attn_kernel<<<dim3(LL / 128, BB * HH), dim3(256), 0, stream>>>(qkv, vt, att);
    // 5. output projection, split-K=2 with fp32 atomic accumulation
    hipMemsetAsync(d_out, 0, (size_t)out_size * sizeof(float), stream);
    gemm_bt_sk<<<dim3(DD / 128, BB * LL / 128, 2), dim3(256), 0, stream>>>(att, woT, (float*)d_out, BB * LL, DD, DD);
}

// Round 8
// 406.435 us; speedup vs baseline: 1.0801x; 1.0801x over previous
//
#include <hip/hip_runtime.h>
#include <math.h>

// Problem constants
#define BB 2
#define LL 2048
#define DD 2048
#define HH 16
#define KVH 8
#define HDIM 128
#define SCALE_F 0.08838834764831845f   // 128^-0.5
#define EPS_F 1e-5f
#define LOG2E 1.4426950408889634f
#define SMAX_F 17.0f                    // fixed softmax max (log2 domain); |s*SC2| <= 16.5
#define QKVW 4096                       // fused qkv row width: 16q + 8k + 8v heads

typedef unsigned short u16;
typedef __attribute__((ext_vector_type(8))) short short8;
typedef __attribute__((ext_vector_type(4))) float f32x4;
typedef __attribute__((ext_vector_type(16))) float f32x16;

#define MFMA16(a, b, c) __builtin_amdgcn_mfma_f32_16x16x32_bf16((a), (b), (c), 0, 0, 0)
#define MFMA32(a, b, c) __builtin_amdgcn_mfma_f32_32x32x16_bf16((a), (b), (c), 0, 0, 0)

__device__ __forceinline__ float b2f(u16 u) {
    union { unsigned int i; float f; } x;
    x.i = ((unsigned int)u) << 16;
    return x.f;
}
__device__ __forceinline__ u16 f2b(float f) {
    unsigned int x = __float_as_uint(f);
    unsigned int r = x + 0x7FFFu + ((x >> 16) & 1u);   // round-to-nearest-even
    return (u16)(r >> 16);
}
__device__ __forceinline__ u16 f2b_fast(float f) {     // round-half-up, 2 VALU
    return (u16)((__float_as_uint(f) + 0x8000u) >> 16);
}
// async global->LDS, 16B per lane; LDS dest = base + lane*16 (HW-fixed)
__device__ __forceinline__ void g2l(const u16* g, u16* l) {
    __builtin_amdgcn_global_load_lds(
        (const __attribute__((address_space(1))) unsigned int*)g,
        (__attribute__((address_space(3))) unsigned int*)l, 16, 0, 0);
}

// ---------------------------------------------------------------------------
// Fused prep: [0,8192) x fp32->bf16 | [8192,11264) weight transposes |
// [11264,11776) rope tables. All independent; one launch.
// ---------------------------------------------------------------------------
__global__ __launch_bounds__(256) void prep_kernel(const float* __restrict__ x,
                                                   u16* __restrict__ xb,
                                                   const float* __restrict__ wq,
                                                   const float* __restrict__ wk,
                                                   const float* __restrict__ wv,
                                                   const float* __restrict__ wo,
                                                   u16* __restrict__ wqkvT,
                                                   u16* __restrict__ woT,
                                                   float* __restrict__ ct,
                                                   float* __restrict__ st) {
    __shared__ u16 t[64 * 65];
    const int blk = blockIdx.x, tid = threadIdx.x;
    if (blk < 8192) {
        // convert x -> bf16
        int i = (blk * 256 + tid) * 4;
        float4 v = *(const float4*)(x + i);
        unsigned int p0 = (unsigned int)f2b(v.x) | ((unsigned int)f2b(v.y) << 16);
        unsigned int p1 = (unsigned int)f2b(v.z) | ((unsigned int)f2b(v.w) << 16);
        uint2 pk; pk.x = p0; pk.y = p1;
        *(uint2*)(xb + i) = pk;
    } else if (blk < 11264) {
        // weight transpose+convert: in [R=2048 rows][C cols] -> out [C][2048]
        int j = blk - 8192;
        const float* in; u16* out; int C, bx, by;
        if (j < 1024)      { in = wq; out = wqkvT;                      C = 2048; bx = j & 31; by = j >> 5; }
        else if (j < 1536) { j -= 1024; in = wk; out = wqkvT + (size_t)2048 * DD; C = 1024; bx = j & 15; by = j >> 4; }
        else if (j < 2048) { j -= 1536; in = wv; out = wqkvT + (size_t)3072 * DD; C = 1024; bx = j & 15; by = j >> 4; }
        else               { j -= 2048; in = wo; out = woT;                      C = 2048; bx = j & 31; by = j >> 5; }
        int c0 = bx * 64, r0 = by * 64;
#pragma unroll
        for (int i = 0; i < 16; i++) {
            int idx = tid + i * 256;
            int r = idx >> 6, c = idx & 63;
            t[r * 65 + c] = f2b(in[(size_t)(r0 + r) * C + c0 + c]);
        }
        __syncthreads();
#pragma unroll
        for (int i = 0; i < 16; i++) {
            int idx = tid + i * 256;
            int r = idx >> 6, c = idx & 63;
            out[(size_t)(c0 + r) * DD + r0 + c] = t[c * 65 + r];
        }
    } else {
        // rope tables, numpy fp32 semantics
        int i = (blk - 11264) * 256 + tid;   // i < LL*64
        int pos = i >> 6, d = i & 63;
        float freq = (float)pow(10000.0, (double)d * (1.0 / 64.0));
        float ang = (float)pos * freq;
        double a = (double)ang;
        ct[i] = (float)cos(a);
        st[i] = (float)sin(a);
    }
}

// ---------------------------------------------------------------------------
// GEMM: C[M,N] = A[M,K] @ Bt[N,K]^T, m97 structure, bf16 out. 128x128 tile.
// ---------------------------------------------------------------------------
__global__ __launch_bounds__(256) void gemm_bt(const u16* __restrict__ A,
                                               const u16* __restrict__ Bt,
                                               u16* __restrict__ C, int M, int N, int K) {
    __shared__ __align__(16) u16 As[128 * 32];
    __shared__ __align__(16) u16 Bs[128 * 32];
    const int tid = threadIdx.x;
    const int w = tid >> 6, lane = tid & 63;
    const int lm = lane & 15, lq = lane >> 4;
    const int bn0 = blockIdx.x * 128, bm0 = blockIdx.y * 128;
    const int wm = (w >> 1) * 64, wn = (w & 1) * 64;

    f32x4 acc[4][4];
#pragma unroll
    for (int i = 0; i < 4; i++)
#pragma unroll
        for (int j = 0; j < 4; j++) acc[i][j] = (f32x4){0.f, 0.f, 0.f, 0.f};

    const int sr = w * 32 + (lane >> 2);
    const int scc = lane & 3;
    const u16* ga = A + (size_t)(bm0 + sr) * K + scc * 8;
    const u16* gb = Bt + (size_t)(bn0 + sr) * K + scc * 8;
    u16* lA = &As[w * 1024];
    u16* lB = &Bs[w * 1024];

    for (int k0 = 0; k0 < K; k0 += 32) {
        __syncthreads();
        g2l(ga + k0, lA);
        g2l(ga + (size_t)16 * K + k0, lA + 512);
        g2l(gb + k0, lB);
        g2l(gb + (size_t)16 * K + k0, lB + 512);
        __syncthreads();

        short8 af[4], bf[4];
#pragma unroll
        for (int mt = 0; mt < 4; mt++)
            af[mt] = *(const short8*)(&As[(wm + mt * 16 + lm) * 32 + lq * 8]);
#pragma unroll
        for (int nt = 0; nt < 4; nt++)
            bf[nt] = *(const short8*)(&Bs[(wn + nt * 16 + lm) * 32 + lq * 8]);
#pragma unroll
        for (int mt = 0; mt < 4; mt++)
#pragma unroll
            for (int nt = 0; nt < 4; nt++) acc[mt][nt] = MFMA16(af[mt], bf[nt], acc[mt][nt]);
    }

#pragma unroll
    for (int mt = 0; mt < 4; mt++)
#pragma unroll
        for (int nt = 0; nt < 4; nt++)
#pragma unroll
            for (int r = 0; r < 4; r++) {
                int row = bm0 + wm + mt * 16 + lq * 4 + r;
                int col = bn0 + wn + nt * 16 + lm;
                C[(size_t)row * N + col] = f2b(acc[mt][nt][r]);
            }
}

// ---------------------------------------------------------------------------
// Output GEMM: 64x128 tile, fp32 direct store. Grid (N/128, M/64) = 1024
// blocks = 4/CU (LDS 12KB, VGPR ~68 -> occupancy bounded by grid only).
// No atomics, no memset — fixes round-7's atomic-epilogue regression while
// keeping the 4/CU overlap that round-6's 2/CU 128x128 version lacked.
// ---------------------------------------------------------------------------
__global__ __launch_bounds__(256) void gemm_bt_o(const u16* __restrict__ A,
                                                 const u16* __restrict__ Bt,
                                                 float* __restrict__ C, int M, int N, int K) {
    __shared__ __align__(16) u16 As[64 * 32];    // 4 KB
    __shared__ __align__(16) u16 Bs[128 * 32];   // 8 KB
    const int tid = threadIdx.x;
    const int w = tid >> 6, lane = tid & 63;
    const int lm = lane & 15, lq = lane >> 4;
    const int bn0 = blockIdx.x * 128, bm0 = blockIdx.y * 64;
    const int wm = (w >> 1) * 32, wn = (w & 1) * 64;

    f32x4 acc[2][4];
#pragma unroll
    for (int i = 0; i < 2; i++)
#pragma unroll
        for (int j = 0; j < 4; j++) acc[i][j] = (f32x4){0.f, 0.f, 0.f, 0.f};

    const int sra = w * 16 + (lane >> 2);        // A: 16 rows/wave
    const int srb = w * 32 + (lane >> 2);        // B: 32 rows/wave (2 chunks)
    const int scc = lane & 3;
    const u16* ga = A + (size_t)(bm0 + sra) * K + scc * 8;
    const u16* gb = Bt + (size_t)(bn0 + srb) * K + scc * 8;
    u16* lA = &As[w * 512];
    u16* lB = &Bs[w * 1024];

    for (int k0 = 0; k0 < K; k0 += 32) {
        __syncthreads();
        g2l(ga + k0, lA);
        g2l(gb + k0, lB);
        g2l(gb + (size_t)16 * K + k0, lB + 512);
        __syncthreads();

        short8 af[2], bf[4];
#pragma unroll
        for (int mt = 0; mt < 2; mt++)
            af[mt] = *(const short8*)(&As[(wm + mt * 16 + lm) * 32 + lq * 8]);
#pragma unroll
        for (int nt = 0; nt < 4; nt++)
            bf[nt] = *(const short8*)(&Bs[(wn + nt * 16 + lm) * 32 + lq * 8]);
#pragma unroll
        for (int mt = 0; mt < 2; mt++)
#pragma unroll
            for (int nt = 0; nt < 4; nt++) acc[mt][nt] = MFMA16(af[mt], bf[nt], acc[mt][nt]);
    }

#pragma unroll
    for (int mt = 0; mt < 2; mt++)
#pragma unroll
        for (int nt = 0; nt < 4; nt++)
#pragma unroll
            for (int r = 0; r < 4; r++) {
                int row = bm0 + wm + mt * 16 + lq * 4 + r;
                int col = bn0 + wn + nt * 16 + lm;
                C[(size_t)row * N + col] = acc[mt][nt][r];
            }
}

// ---------------------------------------------------------------------------
// Fused RoPE+RMSNorm (blocks [0,24576)) + V transpose (blocks [24576,25600)).
// Independent regions of qkv: rope touches cols 0..3071, tv reads 3072..4095.
// ---------------------------------------------------------------------------
__global__ __launch_bounds__(256) void ropetv_kernel(u16* __restrict__ qkv,
                                                     u16* __restrict__ vt,
                                                     const float* __restrict__ qw,
                                                     const float* __restrict__ kw,
                                                     const float* __restrict__ ct,
                                                     const float* __restrict__ st) {
    __shared__ u16 t[64 * 65];
    const int blk = blockIdx.x, tid = threadIdx.x;
    if (blk < 24576) {
        int slot = blk * 4 + (tid >> 6);
        int lane = tid & 63;
        int hh = slot % (HH + KVH);
        int row = slot / (HH + KVH);   // [0, B*L)
        int pos = row & (LL - 1);

        u16* base = qkv + (size_t)row * QKVW + hh * HDIM;
        const float* w = (hh < HH) ? qw : kw;

        float x1 = b2f(base[lane]), x2 = b2f(base[lane + 64]);
        float c = ct[pos * 64 + lane], s = st[pos * 64 + lane];
        float r1 = x1 * c - x2 * s;
        float r2 = x2 * c + x1 * s;
        float ss = r1 * r1 + r2 * r2;
#pragma unroll
        for (int m = 1; m < 64; m <<= 1) ss += __shfl_xor(ss, m, 64);
        float sc = 1.0f / sqrtf(ss * (1.0f / 128.0f) + EPS_F);
        base[lane] = f2b(r1 * sc * w[lane]);
        base[lane + 64] = f2b(r2 * sc * w[lane + 64]);
    } else {
        // V cols of qkv (3072 + g*128 + d) -> vt [b*8+g][d][l]
        int j = blk - 24576;
        int bx = j & 31, by = (j >> 5) & 1, bg = j >> 6;
        int l0 = bx * 64, d0 = by * 64;
        int b = bg >> 3, g = bg & 7;
        const u16* src = qkv + (size_t)b * LL * QKVW + 3072 + g * HDIM;
        u16* dst = vt + (size_t)bg * HDIM * LL;
#pragma unroll
        for (int i = 0; i < 16; i++) {
            int idx = tid + i * 256;
            int r = idx >> 6, c = idx & 63;
            t[r * 65 + c] = src[(size_t)(l0 + r) * QKVW + d0 + c];
        }
        __syncthreads();
#pragma unroll
        for (int i = 0; i < 16; i++) {
            int idx = tid + i * 256;
            int r = idx >> 6, c = idx & 63;   // r = dim, c = key
            dst[(size_t)(d0 + r) * LL + l0 + c] = t[c * 65 + r];
        }
    }
}

// ---------------------------------------------------------------------------
// Flash attention, 32x32x16 MFMA, fixed-max softmax (round-6 verified).
// Block = 256 threads (4 waves) = 128 q-rows. 64-key tiles. 3 barriers/tile
// (barrier (c) is required: P staging ds_write -> ds_read_b128 ordering).
// LDS = 48KB. Grid 512 blocks = 2/CU.
// ---------------------------------------------------------------------------
__global__ __launch_bounds__(256, 2) void attn_kernel(const u16* __restrict__ qkv,
                                                      const u16* __restrict__ vt,
                                                      u16* __restrict__ ob) {
    __shared__ __align__(16) u16 Kt[64 * 128];   // [key][dim] 16 granules/row
    __shared__ __align__(16) u16 Vt[128 * 64];   // [dim][key] 8 granules/row
    __shared__ __align__(16) u16 Ps[4][32 * 64]; // per-wave P, key ^= (row&7)<<3

    const int tid = threadIdx.x, w = tid >> 6, lane = tid & 63;
    const int l31 = lane & 31, lh = lane >> 5;
    const int q0 = blockIdx.x * 128;
    const int bh = blockIdx.y, b = bh >> 4, hd = bh & 15, g = hd >> 1;

    const u16* kbase = qkv + (size_t)b * LL * QKVW + 2048 + g * HDIM;
    const u16* vtbase = vt + (size_t)(b * KVH + g) * HDIM * LL;

    const int krl = lane >> 4, kgl = lane & 15;
    const int vrl = lane >> 3, vgl = lane & 7;

    // Q fragments (A of 32x32x16: m=lane&31, k = kk*16 + lh*8 + j)
    const int qrow = q0 + w * 32 + l31;
    short8 aq[8];
    {
        const u16* qp = qkv + (size_t)(b * LL + qrow) * QKVW + hd * HDIM + lh * 8;
#pragma unroll
        for (int kk = 0; kk < 8; kk++) aq[kk] = *(const short8*)(qp + kk * 16);
    }

    f32x16 o[4];
#pragma unroll
    for (int i = 0; i < 4; i++)
#pragma unroll
        for (int r = 0; r < 16; r++) o[i][r] = 0.f;
    float psum[16];
#pragma unroll
    for (int r = 0; r < 16; r++) psum[r] = 0.f;
    const float SC2 = SCALE_F * LOG2E;

    for (int t = 0; t < LL / 64; t++) {
        __syncthreads();   // (a) prior tile's Kt/Vt fragment reads done
#pragma unroll
        for (int ch = 0; ch < 4; ch++) {
            int r = w * 16 + ch * 4 + krl;
            int gc = kgl ^ (r & 15);
            g2l(kbase + (size_t)(t * 64 + r) * QKVW + gc * 8,
                &Kt[(w * 16 + ch * 4) * 128]);
        }
#pragma unroll
        for (int ch = 0; ch < 4; ch++) {
            int r = w * 32 + ch * 8 + vrl;
            int gc = vgl ^ (r & 7);
            g2l(vtbase + (size_t)r * LL + t * 64 + gc * 8,
                &Vt[(w * 32 + ch * 8) * 64]);
        }
        __syncthreads();   // (b) staging complete

        // S = Q @ K^T  (2 key-tiles of 32)
        f32x16 s[2];
#pragma unroll
        for (int kt = 0; kt < 2; kt++) {
#pragma unroll
            for (int r = 0; r < 16; r++) s[kt][r] = 0.f;
            int key = kt * 32 + l31;
#pragma unroll
            for (int kk = 0; kk < 8; kk++) {
                int gg = (kk * 2 + lh) ^ (key & 15);
                short8 bf = *(const short8*)(&Kt[key * 128 + gg * 8]);
                s[kt] = MFMA32(aq[kk], bf, s[kt]);
            }
        }

        // P = exp2(s*SC2 - 17); lane-partial row sums; stage to per-wave Ps
#pragma unroll
        for (int kt = 0; kt < 2; kt++) {
            int key = kt * 32 + l31;
#pragma unroll
            for (int r = 0; r < 16; r++) {
                float p = exp2f(fmaf(s[kt][r], SC2, -SMAX_F));
                psum[r] += p;
                int row = (r & 3) + 8 * (r >> 2) + 4 * lh;
                Ps[w][row * 64 + (key ^ ((row & 7) << 3))] = f2b_fast(p);
            }
        }
        __syncthreads();   // (c) required: P writes visible before b128 reads

        // O += P @ V
#pragma unroll
        for (int kc = 0; kc < 4; kc++) {
            int gp = ((kc * 2 + lh) ^ (l31 & 7)) * 8;
            short8 pa = *(const short8*)(&Ps[w][l31 * 64 + gp]);
#pragma unroll
            for (int dn = 0; dn < 4; dn++) {
                int d = dn * 32 + l31;
                int gv = ((kc * 2 + lh) ^ (d & 7)) * 8;
                short8 bv = *(const short8*)(&Vt[d * 64 + gv]);
                o[dn] = MFMA32(pa, bv, o[dn]);
            }
        }
    }

    // deferred row-sum reduce across the 32 lanes sharing lh
#pragma unroll
    for (int m = 1; m < 32; m <<= 1)
#pragma unroll
        for (int r = 0; r < 16; r++) psum[r] += __shfl_xor(psum[r], m, 32);
    float inv[16];
#pragma unroll
    for (int r = 0; r < 16; r++) inv[r] = 1.0f / psum[r];

    // O: col = dim = dn*32 + l31, row = (r&3)+8*(r>>2)+4*lh
    u16* obase = ob + (size_t)(b * LL + q0 + w * 32) * (HH * HDIM) + hd * HDIM;
#pragma unroll
    for (int dn = 0; dn < 4; dn++)
#pragma unroll
        for (int r = 0; r < 16; r++) {
            int row = (r & 3) + 8 * (r >> 2) + 4 * lh;
            obase[(size_t)row * (HH * HDIM) + dn * 32 + l31] = f2b(o[dn][r] * inv[r]);
        }
}

// ---------------------------------------------------------------------------
extern "C" void kernel_launch(void* const* d_in, const int* in_sizes, int n_in,
                              void* d_out, int out_size, void* d_ws, size_t ws_size,
                              hipStream_t stream) {
    const float* x  = (const float*)d_in[0];
    const float* wq = (const float*)d_in[1];
    const float* wk = (const float*)d_in[2];
    const float* wv = (const float*)d_in[3];
    const float* wo = (const float*)d_in[4];
    const float* qn = (const float*)d_in[5];
    const float* kn = (const float*)d_in[6];

    u16* ws = (u16*)d_ws;
    const size_t SZ_X = (size_t)BB * LL * DD;          // 8388608
    u16* xb    = ws;                         // SZ_X (later reused as att)
    u16* qkv   = xb + SZ_X;                  // B*L*4096 = 16.8M
    u16* wqkvT = qkv + (size_t)BB * LL * QKVW;  // 4096*2048 (later reused as vt)
    u16* woT   = wqkvT + (size_t)QKVW * DD;  // 2048*2048
    float* ct  = (float*)(woT + (size_t)DD * DD);   // LL*64 floats
    float* st  = ct + (size_t)LL * 64;
    u16* att = xb;
    u16* vt  = wqkvT;   // dead after fused QKV GEMM

    // 1. fused prep: x convert + 4 weight transposes + rope tables
    prep_kernel<<<dim3(11776), dim3(256), 0, stream>>>(x, xb, wq, wk, wv, wo,
                                                       wqkvT, woT, ct, st);
    // 2. fused QKV projection: [B*L, 4096] = xb @ wqkvT^T
    gemm_bt<<<dim3(QKVW / 128, BB * LL / 128), dim3(256), 0, stream>>>(xb, wqkvT, qkv, BB * LL, QKVW, DD);
    // 3. fused rope+rmsnorm (q,k) + V transpose
    ropetv_kernel<<<dim3(25600), dim3(256), 0, stream>>>(qkv, vt, qn, kn, ct, st);
    // 4. attention
    attn_kernel<<<dim3(LL / 128, BB * HH), dim3(256), 0, stream>>>(qkv, vt, att);
    // 5. output projection: 64x128 tile, 1024 blocks = 4/CU, direct fp32 store
    gemm_bt_o<<<dim3(DD / 128, BB * LL / 64), dim3(256), 0, stream>>>(att, woT, (float*)d_out, BB * LL, DD, DD);
}

// Round 9
// 391.344 us; speedup vs baseline: 1.1218x; 1.0386x over previous
//
#include <hip/hip_runtime.h>
#include <math.h>

// Problem constants
#define BB 2
#define LL 2048
#define DD 2048
#define HH 16
#define KVH 8
#define HDIM 128
#define SCALE_F 0.08838834764831845f   // 128^-0.5
#define EPS_F 1e-5f
#define LOG2E 1.4426950408889634f
#define SMAX_F 17.0f                    // fixed softmax max (log2 domain); |s*SC2| <= 16.5
#define QKVW 4096                       // fused qkv row width: 16q + 8k + 8v heads

typedef unsigned short u16;
typedef __attribute__((ext_vector_type(8))) short short8;
typedef __attribute__((ext_vector_type(4))) float f32x4;
typedef __attribute__((ext_vector_type(16))) float f32x16;

#define MFMA16(a, b, c) __builtin_amdgcn_mfma_f32_16x16x32_bf16((a), (b), (c), 0, 0, 0)
#define MFMA32(a, b, c) __builtin_amdgcn_mfma_f32_32x32x16_bf16((a), (b), (c), 0, 0, 0)

__device__ __forceinline__ float b2f(u16 u) {
    union { unsigned int i; float f; } x;
    x.i = ((unsigned int)u) << 16;
    return x.f;
}
__device__ __forceinline__ u16 f2b(float f) {
    unsigned int x = __float_as_uint(f);
    unsigned int r = x + 0x7FFFu + ((x >> 16) & 1u);   // round-to-nearest-even
    return (u16)(r >> 16);
}
__device__ __forceinline__ u16 f2b_fast(float f) {     // round-half-up, 2 VALU
    return (u16)((__float_as_uint(f) + 0x8000u) >> 16);
}
// async global->LDS, 16B per lane; LDS dest = base + lane*16 (HW-fixed)
__device__ __forceinline__ void g2l(const u16* g, u16* l) {
    __builtin_amdgcn_global_load_lds(
        (const __attribute__((address_space(1))) unsigned int*)g,
        (__attribute__((address_space(3))) unsigned int*)l, 16, 0, 0);
}

// ---------------------------------------------------------------------------
// Fused prep: [0,8192) x fp32->bf16 | [8192,11264) weight transposes |
// [11264,11776) rope tables. All independent; one launch.
// ---------------------------------------------------------------------------
__global__ __launch_bounds__(256) void prep_kernel(const float* __restrict__ x,
                                                   u16* __restrict__ xb,
                                                   const float* __restrict__ wq,
                                                   const float* __restrict__ wk,
                                                   const float* __restrict__ wv,
                                                   const float* __restrict__ wo,
                                                   u16* __restrict__ wqkvT,
                                                   u16* __restrict__ woT,
                                                   float* __restrict__ ct,
                                                   float* __restrict__ st) {
    __shared__ u16 t[64 * 65];
    const int blk = blockIdx.x, tid = threadIdx.x;
    if (blk < 8192) {
        // convert x -> bf16
        int i = (blk * 256 + tid) * 4;
        float4 v = *(const float4*)(x + i);
        unsigned int p0 = (unsigned int)f2b(v.x) | ((unsigned int)f2b(v.y) << 16);
        unsigned int p1 = (unsigned int)f2b(v.z) | ((unsigned int)f2b(v.w) << 16);
        uint2 pk; pk.x = p0; pk.y = p1;
        *(uint2*)(xb + i) = pk;
    } else if (blk < 11264) {
        // weight transpose+convert: in [R=2048 rows][C cols] -> out [C][2048]
        int j = blk - 8192;
        const float* in; u16* out; int C, bx, by;
        if (j < 1024)      { in = wq; out = wqkvT;                      C = 2048; bx = j & 31; by = j >> 5; }
        else if (j < 1536) { j -= 1024; in = wk; out = wqkvT + (size_t)2048 * DD; C = 1024; bx = j & 15; by = j >> 4; }
        else if (j < 2048) { j -= 1536; in = wv; out = wqkvT + (size_t)3072 * DD; C = 1024; bx = j & 15; by = j >> 4; }
        else               { j -= 2048; in = wo; out = woT;                      C = 2048; bx = j & 31; by = j >> 5; }
        int c0 = bx * 64, r0 = by * 64;
#pragma unroll
        for (int i = 0; i < 16; i++) {
            int idx = tid + i * 256;
            int r = idx >> 6, c = idx & 63;
            t[r * 65 + c] = f2b(in[(size_t)(r0 + r) * C + c0 + c]);
        }
        __syncthreads();
#pragma unroll
        for (int i = 0; i < 16; i++) {
            int idx = tid + i * 256;
            int r = idx >> 6, c = idx & 63;
            out[(size_t)(c0 + r) * DD + r0 + c] = t[c * 65 + r];
        }
    } else {
        // rope tables, numpy fp32 semantics
        int i = (blk - 11264) * 256 + tid;   // i < LL*64
        int pos = i >> 6, d = i & 63;
        float freq = (float)pow(10000.0, (double)d * (1.0 / 64.0));
        float ang = (float)pos * freq;
        double a = (double)ang;
        ct[i] = (float)cos(a);
        st[i] = (float)sin(a);
    }
}

// ---------------------------------------------------------------------------
// QKV GEMM: C[M,N] = A[M,K] @ Bt[N,K]^T, bf16 out. 128x128 tile, BK=64
// (half the barrier drains of BK=32; LDS 32KB keeps 4 blocks/CU).
// 128-B LDS rows XOR-granule-swizzled (g ^= row&7) in the global source
// address so both the g2l writes and b128 fragment reads are conflict-free.
// ---------------------------------------------------------------------------
__global__ __launch_bounds__(256) void gemm_bt(const u16* __restrict__ A,
                                               const u16* __restrict__ Bt,
                                               u16* __restrict__ C, int M, int N, int K) {
    __shared__ __align__(16) u16 As[128 * 64];   // 16 KB
    __shared__ __align__(16) u16 Bs[128 * 64];   // 16 KB
    const int tid = threadIdx.x;
    const int w = tid >> 6, lane = tid & 63;
    const int lm = lane & 15, lq = lane >> 4;
    const int bn0 = blockIdx.x * 128, bm0 = blockIdx.y * 128;
    const int wm = (w >> 1) * 64, wn = (w & 1) * 64;

    f32x4 acc[4][4];
#pragma unroll
    for (int i = 0; i < 4; i++)
#pragma unroll
        for (int j = 0; j < 4; j++) acc[i][j] = (f32x4){0.f, 0.f, 0.f, 0.f};

    // staging: wave w stages rows [w*32, w*32+32) of A and B, 4 g2l each.
    // lane -> row (lane>>3) within 8-row chunk, granule (lane&7)^(row&7)
    const int srow = lane >> 3;
    const int sgr = (lane & 7) ^ (srow & 7);
    const u16* ga = A + (size_t)(bm0 + w * 32 + srow) * K + sgr * 8;
    const u16* gb = Bt + (size_t)(bn0 + w * 32 + srow) * K + sgr * 8;
    u16* lA = &As[(w * 32) * 64];
    u16* lB = &Bs[(w * 32) * 64];

    for (int k0 = 0; k0 < K; k0 += 64) {
        __syncthreads();
#pragma unroll
        for (int ch = 0; ch < 4; ch++)
            g2l(ga + (size_t)(ch * 8) * K + k0, lA + ch * 8 * 64);
#pragma unroll
        for (int ch = 0; ch < 4; ch++)
            g2l(gb + (size_t)(ch * 8) * K + k0, lB + ch * 8 * 64);
        __syncthreads();

#pragma unroll
        for (int sub = 0; sub < 2; sub++) {
            short8 af[4], bf[4];
#pragma unroll
            for (int mt = 0; mt < 4; mt++) {
                int row = wm + mt * 16 + lm;
                af[mt] = *(const short8*)(&As[row * 64 + ((sub * 4 + lq) ^ (lm & 7)) * 8]);
            }
#pragma unroll
            for (int nt = 0; nt < 4; nt++) {
                int row = wn + nt * 16 + lm;
                bf[nt] = *(const short8*)(&Bs[row * 64 + ((sub * 4 + lq) ^ (lm & 7)) * 8]);
            }
#pragma unroll
            for (int mt = 0; mt < 4; mt++)
#pragma unroll
                for (int nt = 0; nt < 4; nt++) acc[mt][nt] = MFMA16(af[mt], bf[nt], acc[mt][nt]);
        }
    }

#pragma unroll
    for (int mt = 0; mt < 4; mt++)
#pragma unroll
        for (int nt = 0; nt < 4; nt++)
#pragma unroll
            for (int r = 0; r < 4; r++) {
                int row = bm0 + wm + mt * 16 + lq * 4 + r;
                int col = bn0 + wn + nt * 16 + lm;
                C[(size_t)row * N + col] = f2b(acc[mt][nt][r]);
            }
}

// ---------------------------------------------------------------------------
// Output GEMM: 64x128 tile, BK=64, fp32 direct store. Grid (16,64) = 1024
// blocks = 4/CU; LDS 24KB. Same XOR-granule swizzle as gemm_bt.
// ---------------------------------------------------------------------------
__global__ __launch_bounds__(256) void gemm_bt_o(const u16* __restrict__ A,
                                                 const u16* __restrict__ Bt,
                                                 float* __restrict__ C, int M, int N, int K) {
    __shared__ __align__(16) u16 As[64 * 64];    // 8 KB
    __shared__ __align__(16) u16 Bs[128 * 64];   // 16 KB
    const int tid = threadIdx.x;
    const int w = tid >> 6, lane = tid & 63;
    const int lm = lane & 15, lq = lane >> 4;
    const int bn0 = blockIdx.x * 128, bm0 = blockIdx.y * 64;
    const int wm = (w >> 1) * 32, wn = (w & 1) * 64;

    f32x4 acc[2][4];
#pragma unroll
    for (int i = 0; i < 2; i++)
#pragma unroll
        for (int j = 0; j < 4; j++) acc[i][j] = (f32x4){0.f, 0.f, 0.f, 0.f};

    const int srow = lane >> 3;
    const int sgr = (lane & 7) ^ (srow & 7);
    const u16* ga = A + (size_t)(bm0 + w * 16 + srow) * K + sgr * 8;   // 16 A-rows/wave
    const u16* gb = Bt + (size_t)(bn0 + w * 32 + srow) * K + sgr * 8;  // 32 B-rows/wave
    u16* lA = &As[(w * 16) * 64];
    u16* lB = &Bs[(w * 32) * 64];

    for (int k0 = 0; k0 < K; k0 += 64) {
        __syncthreads();
#pragma unroll
        for (int ch = 0; ch < 2; ch++)
            g2l(ga + (size_t)(ch * 8) * K + k0, lA + ch * 8 * 64);
#pragma unroll
        for (int ch = 0; ch < 4; ch++)
            g2l(gb + (size_t)(ch * 8) * K + k0, lB + ch * 8 * 64);
        __syncthreads();

#pragma unroll
        for (int sub = 0; sub < 2; sub++) {
            short8 af[2], bf[4];
#pragma unroll
            for (int mt = 0; mt < 2; mt++) {
                int row = wm + mt * 16 + lm;
                af[mt] = *(const short8*)(&As[row * 64 + ((sub * 4 + lq) ^ (lm & 7)) * 8]);
            }
#pragma unroll
            for (int nt = 0; nt < 4; nt++) {
                int row = wn + nt * 16 + lm;
                bf[nt] = *(const short8*)(&Bs[row * 64 + ((sub * 4 + lq) ^ (lm & 7)) * 8]);
            }
#pragma unroll
            for (int mt = 0; mt < 2; mt++)
#pragma unroll
                for (int nt = 0; nt < 4; nt++) acc[mt][nt] = MFMA16(af[mt], bf[nt], acc[mt][nt]);
        }
    }

#pragma unroll
    for (int mt = 0; mt < 2; mt++)
#pragma unroll
        for (int nt = 0; nt < 4; nt++)
#pragma unroll
            for (int r = 0; r < 4; r++) {
                int row = bm0 + wm + mt * 16 + lq * 4 + r;
                int col = bn0 + wn + nt * 16 + lm;
                C[(size_t)row * N + col] = acc[mt][nt][r];
            }
}

// ---------------------------------------------------------------------------
// Fused RoPE+RMSNorm (blocks [0,24576)) + V transpose (blocks [24576,25600)).
// Independent regions of qkv: rope touches cols 0..3071, tv reads 3072..4095.
// ---------------------------------------------------------------------------
__global__ __launch_bounds__(256) void ropetv_kernel(u16* __restrict__ qkv,
                                                     u16* __restrict__ vt,
                                                     const float* __restrict__ qw,
                                                     const float* __restrict__ kw,
                                                     const float* __restrict__ ct,
                                                     const float* __restrict__ st) {
    __shared__ u16 t[64 * 65];
    const int blk = blockIdx.x, tid = threadIdx.x;
    if (blk < 24576) {
        int slot = blk * 4 + (tid >> 6);
        int lane = tid & 63;
        int hh = slot % (HH + KVH);
        int row = slot / (HH + KVH);   // [0, B*L)
        int pos = row & (LL - 1);

        u16* base = qkv + (size_t)row * QKVW + hh * HDIM;
        const float* w = (hh < HH) ? qw : kw;

        float x1 = b2f(base[lane]), x2 = b2f(base[lane + 64]);
        float c = ct[pos * 64 + lane], s = st[pos * 64 + lane];
        float r1 = x1 * c - x2 * s;
        float r2 = x2 * c + x1 * s;
        float ss = r1 * r1 + r2 * r2;
#pragma unroll
        for (int m = 1; m < 64; m <<= 1) ss += __shfl_xor(ss, m, 64);
        float sc = 1.0f / sqrtf(ss * (1.0f / 128.0f) + EPS_F);
        base[lane] = f2b(r1 * sc * w[lane]);
        base[lane + 64] = f2b(r2 * sc * w[lane + 64]);
    } else {
        // V cols of qkv (3072 + g*128 + d) -> vt [b*8+g][d][l]
        int j = blk - 24576;
        int bx = j & 31, by = (j >> 5) & 1, bg = j >> 6;
        int l0 = bx * 64, d0 = by * 64;
        int b = bg >> 3, g = bg & 7;
        const u16* src = qkv + (size_t)b * LL * QKVW + 3072 + g * HDIM;
        u16* dst = vt + (size_t)bg * HDIM * LL;
#pragma unroll
        for (int i = 0; i < 16; i++) {
            int idx = tid + i * 256;
            int r = idx >> 6, c = idx & 63;
            t[r * 65 + c] = src[(size_t)(l0 + r) * QKVW + d0 + c];
        }
        __syncthreads();
#pragma unroll
        for (int i = 0; i < 16; i++) {
            int idx = tid + i * 256;
            int r = idx >> 6, c = idx & 63;   // r = dim, c = key
            dst[(size_t)(d0 + r) * LL + l0 + c] = t[c * 65 + r];
        }
    }
}

// ---------------------------------------------------------------------------
// Flash attention, 32x32x16 MFMA, fixed-max softmax (round-6/8 verified).
// Block = 256 threads (4 waves) = 128 q-rows. 64-key tiles. 3 barriers/tile
// (barrier (c) is required: P staging ds_write -> ds_read_b128 ordering).
// LDS = 48KB. Grid 512 blocks = 2/CU.
// ---------------------------------------------------------------------------
__global__ __launch_bounds__(256, 2) void attn_kernel(const u16* __restrict__ qkv,
                                                      const u16* __restrict__ vt,
                                                      u16* __restrict__ ob) {
    __shared__ __align__(16) u16 Kt[64 * 128];   // [key][dim] 16 granules/row
    __shared__ __align__(16) u16 Vt[128 * 64];   // [dim][key] 8 granules/row
    __shared__ __align__(16) u16 Ps[4][32 * 64]; // per-wave P, key ^= (row&7)<<3

    const int tid = threadIdx.x, w = tid >> 6, lane = tid & 63;
    const int l31 = lane & 31, lh = lane >> 5;
    const int q0 = blockIdx.x * 128;
    const int bh = blockIdx.y, b = bh >> 4, hd = bh & 15, g = hd >> 1;

    const u16* kbase = qkv + (size_t)b * LL * QKVW + 2048 + g * HDIM;
    const u16* vtbase = vt + (size_t)(b * KVH + g) * HDIM * LL;

    const int krl = lane >> 4, kgl = lane & 15;
    const int vrl = lane >> 3, vgl = lane & 7;

    // Q fragments (A of 32x32x16: m=lane&31, k = kk*16 + lh*8 + j)
    const int qrow = q0 + w * 32 + l31;
    short8 aq[8];
    {
        const u16* qp = qkv + (size_t)(b * LL + qrow) * QKVW + hd * HDIM + lh * 8;
#pragma unroll
        for (int kk = 0; kk < 8; kk++) aq[kk] = *(const short8*)(qp + kk * 16);
    }

    f32x16 o[4];
#pragma unroll
    for (int i = 0; i < 4; i++)
#pragma unroll
        for (int r = 0; r < 16; r++) o[i][r] = 0.f;
    float psum[16];
#pragma unroll
    for (int r = 0; r < 16; r++) psum[r] = 0.f;
    const float SC2 = SCALE_F * LOG2E;

    for (int t = 0; t < LL / 64; t++) {
        __syncthreads();   // (a) prior tile's Kt/Vt fragment reads done
#pragma unroll
        for (int ch = 0; ch < 4; ch++) {
            int r = w * 16 + ch * 4 + krl;
            int gc = kgl ^ (r & 15);
            g2l(kbase + (size_t)(t * 64 + r) * QKVW + gc * 8,
                &Kt[(w * 16 + ch * 4) * 128]);
        }
#pragma unroll
        for (int ch = 0; ch < 4; ch++) {
            int r = w * 32 + ch * 8 + vrl;
            int gc = vgl ^ (r & 7);
            g2l(vtbase + (size_t)r * LL + t * 64 + gc * 8,
                &Vt[(w * 32 + ch * 8) * 64]);
        }
        __syncthreads();   // (b) staging complete

        // S = Q @ K^T  (2 key-tiles of 32)
        f32x16 s[2];
#pragma unroll
        for (int kt = 0; kt < 2; kt++) {
#pragma unroll
            for (int r = 0; r < 16; r++) s[kt][r] = 0.f;
            int key = kt * 32 + l31;
#pragma unroll
            for (int kk = 0; kk < 8; kk++) {
                int gg = (kk * 2 + lh) ^ (key & 15);
                short8 bf = *(const short8*)(&Kt[key * 128 + gg * 8]);
                s[kt] = MFMA32(aq[kk], bf, s[kt]);
            }
        }

        // P = exp2(s*SC2 - 17); lane-partial row sums; stage to per-wave Ps
#pragma unroll
        for (int kt = 0; kt < 2; kt++) {
            int key = kt * 32 + l31;
#pragma unroll
            for (int r = 0; r < 16; r++) {
                float p = exp2f(fmaf(s[kt][r], SC2, -SMAX_F));
                psum[r] += p;
                int row = (r & 3) + 8 * (r >> 2) + 4 * lh;
                Ps[w][row * 64 + (key ^ ((row & 7) << 3))] = f2b_fast(p);
            }
        }
        __syncthreads();   // (c) required: P writes visible before b128 reads

        // O += P @ V
#pragma unroll
        for (int kc = 0; kc < 4; kc++) {
            int gp = ((kc * 2 + lh) ^ (l31 & 7)) * 8;
            short8 pa = *(const short8*)(&Ps[w][l31 * 64 + gp]);
#pragma unroll
            for (int dn = 0; dn < 4; dn++) {
                int d = dn * 32 + l31;
                int gv = ((kc * 2 + lh) ^ (d & 7)) * 8;
                short8 bv = *(const short8*)(&Vt[d * 64 + gv]);
                o[dn] = MFMA32(pa, bv, o[dn]);
            }
        }
    }

    // deferred row-sum reduce across the 32 lanes sharing lh
#pragma unroll
    for (int m = 1; m < 32; m <<= 1)
#pragma unroll
        for (int r = 0; r < 16; r++) psum[r] += __shfl_xor(psum[r], m, 32);
    float inv[16];
#pragma unroll
    for (int r = 0; r < 16; r++) inv[r] = 1.0f / psum[r];

    // O: col = dim = dn*32 + l31, row = (r&3)+8*(r>>2)+4*lh
    u16* obase = ob + (size_t)(b * LL + q0 + w * 32) * (HH * HDIM) + hd * HDIM;
#pragma unroll
    for (int dn = 0; dn < 4; dn++)
#pragma unroll
        for (int r = 0; r < 16; r++) {
            int row = (r & 3) + 8 * (r >> 2) + 4 * lh;
            obase[(size_t)row * (HH * HDIM) + dn * 32 + l31] = f2b(o[dn][r] * inv[r]);
        }
}

// ---------------------------------------------------------------------------
extern "C" void kernel_launch(void* const* d_in, const int* in_sizes, int n_in,
                              void* d_out, int out_size, void* d_ws, size_t ws_size,
                              hipStream_t stream) {
    const float* x  = (const float*)d_in[0];
    const float* wq = (const float*)d_in[1];
    const float* wk = (const float*)d_in[2];
    const float* wv = (const float*)d_in[3];
    const float* wo = (const float*)d_in[4];
    const float* qn = (const float*)d_in[5];
    const float* kn = (const float*)d_in[6];

    u16* ws = (u16*)d_ws;
    const size_t SZ_X = (size_t)BB * LL * DD;          // 8388608
    u16* xb    = ws;                         // SZ_X (later reused as att)
    u16* qkv   = xb + SZ_X;                  // B*L*4096 = 16.8M
    u16* wqkvT = qkv + (size_t)BB * LL * QKVW;  // 4096*2048 (later reused as vt)
    u16* woT   = wqkvT + (size_t)QKVW * DD;  // 2048*2048
    float* ct  = (float*)(woT + (size_t)DD * DD);   // LL*64 floats
    float* st  = ct + (size_t)LL * 64;
    u16* att = xb;
    u16* vt  = wqkvT;   // dead after fused QKV GEMM

    // 1. fused prep: x convert + 4 weight transposes + rope tables
    prep_kernel<<<dim3(11776), dim3(256), 0, stream>>>(x, xb, wq, wk, wv, wo,
                                                       wqkvT, woT, ct, st);
    // 2. fused QKV projection: [B*L, 4096] = xb @ wqkvT^T  (BK=64)
    gemm_bt<<<dim3(QKVW / 128, BB * LL / 128), dim3(256), 0, stream>>>(xb, wqkvT, qkv, BB * LL, QKVW, DD);
    // 3. fused rope+rmsnorm (q,k) + V transpose
    ropetv_kernel<<<dim3(25600), dim3(256), 0, stream>>>(qkv, vt, qn, kn, ct, st);
    // 4. attention
    attn_kernel<<<dim3(LL / 128, BB * HH), dim3(256), 0, stream>>>(qkv, vt, att);
    // 5. output projection: 64x128 tile, BK=64, 1024 blocks = 4/CU, fp32 store
    gemm_bt_o<<<dim3(DD / 128, BB * LL / 64), dim3(256), 0, stream>>>(att, woT, (float*)d_out, BB * LL, DD, DD);
}